// Round 1
// baseline (1124.644 us; speedup 1.0000x reference)
//
#include <hip/hip_runtime.h>

#define B_   2
#define D_   32
#define H_   256
#define W_   256
#define N_   150000
#define CIN  16
#define CMID 32
#define COUT 64
#define DO_  16
#define HO_  128
#define WO_  128
#define M_   (B_*DO_*HO_*WO_)   /* 524288 */
#define EPSf 1e-5f

// ---------------- grid scatter ----------------
__global__ __launch_bounds__(256) void k_scatter(const int* __restrict__ coords,
                                                 int* __restrict__ grid) {
    int i = blockIdx.x * 256 + threadIdx.x;
    if (i >= N_) return;
    const int4 c = *(const int4*)(coords + 4 * (size_t)i);
    grid[((c.x * D_ + c.y) * H_ + c.z) * W_ + c.w] = i;
}

// ---------------- submanifold conv (gather) ----------------
template <int CI, int CO>
__global__ __launch_bounds__(256) void k_subm(const float* __restrict__ X,
                                              const int* __restrict__ coords,
                                              const int* __restrict__ grid,
                                              const float* __restrict__ Wk,
                                              const float* __restrict__ bias,
                                              float* __restrict__ Y) {
    const int i = blockIdx.x * 256 + threadIdx.x;
    float acc[CO];
#pragma unroll
    for (int c = 0; c < CO; ++c) acc[c] = 0.f;

    int cb = 0, cz = 0, cy = 0, cx = 0;
    const bool live = (i < N_);
    if (live) {
        const int4 c4 = *(const int4*)(coords + 4 * (size_t)i);
        cb = c4.x; cz = c4.y; cy = c4.z; cx = c4.w;
    }

    for (int ki = 0; ki < 27; ++ki) {
        const int dz = ki / 9 - 1, dy = (ki / 3) % 3 - 1, dx = ki % 3 - 1;
        const int nz = cz + dz, ny = cy + dy, nx = cx + dx;
        int nidx = -1;
        if (live && (unsigned)nz < (unsigned)D_ && (unsigned)ny < (unsigned)H_ &&
            (unsigned)nx < (unsigned)W_)
            nidx = grid[((cb * D_ + nz) * H_ + ny) * W_ + nx];
        if (nidx >= 0) {
            const float* __restrict__ f = X + (size_t)nidx * CI;
            const float* __restrict__ w = Wk + (size_t)ki * CI * CO;
            float fv[CI];
#pragma unroll
            for (int ci = 0; ci < CI; ci += 4) {
                const float4 t = *(const float4*)(f + ci);
                fv[ci] = t.x; fv[ci + 1] = t.y; fv[ci + 2] = t.z; fv[ci + 3] = t.w;
            }
#pragma unroll
            for (int ci = 0; ci < CI; ++ci)
#pragma unroll
                for (int co = 0; co < CO; ++co)
                    acc[co] = fmaf(fv[ci], w[ci * CO + co], acc[co]);
        }
    }

    if (live) {
#pragma unroll
        for (int co = 0; co < CO; co += 4) {
            float4 o;
            o.x = acc[co]     + bias[co];
            o.y = acc[co + 1] + bias[co + 1];
            o.z = acc[co + 2] + bias[co + 2];
            o.w = acc[co + 3] + bias[co + 3];
            *(float4*)(Y + (size_t)i * CO + co) = o;
        }
    }
}

// ---------------- strided down conv (gather over output voxels) ----------------
__global__ __launch_bounds__(256) void k_down(const float* __restrict__ X,
                                              const int* __restrict__ grid,
                                              const float* __restrict__ Wk,
                                              const float* __restrict__ bias,
                                              float* __restrict__ Y,
                                              unsigned char* __restrict__ mask) {
    const int o = blockIdx.x * 256 + threadIdx.x;
    if (o >= M_) return;
    const int ox = o % WO_;
    int t = o / WO_;
    const int oy = t % HO_;
    t /= HO_;
    const int oz = t % DO_;
    const int b  = t / DO_;

    float acc[COUT];
#pragma unroll
    for (int c = 0; c < COUT; ++c) acc[c] = 0.f;
    int cnt = 0;

    for (int ki = 0; ki < 27; ++ki) {
        const int kz = ki / 9, ky = (ki / 3) % 3, kx = ki % 3;
        const int z = 2 * oz - 1 + kz, y = 2 * oy - 1 + ky, x = 2 * ox - 1 + kx;
        int nidx = -1;
        if ((unsigned)z < (unsigned)D_ && (unsigned)y < (unsigned)H_ &&
            (unsigned)x < (unsigned)W_)
            nidx = grid[((b * D_ + z) * H_ + y) * W_ + x];
        if (nidx >= 0) {
            ++cnt;
            const float* __restrict__ f = X + (size_t)nidx * CMID;
            const float* __restrict__ w = Wk + (size_t)ki * CMID * COUT;
            float fv[CMID];
#pragma unroll
            for (int ci = 0; ci < CMID; ci += 4) {
                const float4 tt = *(const float4*)(f + ci);
                fv[ci] = tt.x; fv[ci + 1] = tt.y; fv[ci + 2] = tt.z; fv[ci + 3] = tt.w;
            }
#pragma unroll
            for (int ci = 0; ci < CMID; ++ci)
#pragma unroll
                for (int co = 0; co < COUT; ++co)
                    acc[co] = fmaf(fv[ci], w[ci * COUT + co], acc[co]);
        }
    }

    const unsigned char mk = (cnt > 0) ? 1 : 0;
    mask[o] = mk;
#pragma unroll
    for (int co = 0; co < COUT; co += 4) {
        float4 ov;
        if (mk) {
            ov.x = acc[co]     + bias[co];
            ov.y = acc[co + 1] + bias[co + 1];
            ov.z = acc[co + 2] + bias[co + 2];
            ov.w = acc[co + 3] + bias[co + 3];
        } else {
            ov.x = ov.y = ov.z = ov.w = 0.f;
        }
        *(float4*)(Y + (size_t)o * COUT + co) = ov;
    }
}

// ---------------- per-channel sum / sumsq ----------------
template <int C>
__global__ __launch_bounds__(256) void k_stats(const float* __restrict__ Y,
                                               long n_elems,
                                               float* __restrict__ stats) {
    __shared__ float sdata[256];
    const int t = threadIdx.x;
    const long stride = (long)gridDim.x * 256;
    float s = 0.f, s2 = 0.f;
    for (long idx = (long)blockIdx.x * 256 + t; idx < n_elems; idx += stride) {
        const float v = Y[idx];
        s += v; s2 += v * v;
    }
    sdata[t] = s; __syncthreads();
    for (int off = 128; off >= C; off >>= 1) {
        if (t < off) sdata[t] += sdata[t + off];
        __syncthreads();
    }
    if (t < C) atomicAdd(stats + t, sdata[t]);
    __syncthreads();
    sdata[t] = s2; __syncthreads();
    for (int off = 128; off >= C; off >>= 1) {
        if (t < off) sdata[t] += sdata[t + off];
        __syncthreads();
    }
    if (t < C) atomicAdd(stats + C + t, sdata[t]);
}

// stage-3 stats: inactive voxels hold 0 so sums need no mask; nact does.
__global__ __launch_bounds__(256) void k_stats3(const float* __restrict__ Y,
                                                const unsigned char* __restrict__ mask,
                                                float* __restrict__ stats,
                                                int* __restrict__ nact) {
    __shared__ float sdata[256];
    __shared__ int   scnt[256];
    const int t = threadIdx.x;
    const long total  = (long)M_ * COUT;
    const long stride = (long)gridDim.x * 256;
    float s = 0.f, s2 = 0.f;
    int cnt = 0;
    for (long idx = (long)blockIdx.x * 256 + t; idx < total; idx += stride) {
        const float v = Y[idx];
        s += v; s2 += v * v;
        if ((idx & 63) == 0) cnt += mask[idx >> 6];
    }
    sdata[t] = s; __syncthreads();
    for (int off = 128; off >= 64; off >>= 1) {
        if (t < off) sdata[t] += sdata[t + off];
        __syncthreads();
    }
    if (t < 64) atomicAdd(stats + t, sdata[t]);
    __syncthreads();
    sdata[t] = s2; __syncthreads();
    for (int off = 128; off >= 64; off >>= 1) {
        if (t < off) sdata[t] += sdata[t + off];
        __syncthreads();
    }
    if (t < 64) atomicAdd(stats + 64 + t, sdata[t]);
    __syncthreads();
    scnt[t] = cnt; __syncthreads();
    for (int off = 128; off >= 1; off >>= 1) {
        if (t < off) scnt[t] += scnt[t + off];
        __syncthreads();
    }
    if (t == 0) atomicAdd(nact, scnt[0]);
}

// ---------------- finalize scale/shift ----------------
template <int C>
__global__ void k_finstats(const float* __restrict__ stats,
                           const float* __restrict__ g,
                           const float* __restrict__ be,
                           float nfix, const int* __restrict__ nact,
                           float* __restrict__ ss) {
    const int c = threadIdx.x;
    if (c >= C) return;
    float n = nfix;
    if (nact) { int na = *nact; n = (float)(na > 0 ? na : 1); }
    const float m  = stats[c] / n;
    const float v  = stats[C + c] / n - m * m;
    const float sc = g[c] * rsqrtf(v + EPSf);
    ss[c]     = sc;
    ss[C + c] = be[c] - m * sc;
}

// ---------------- normalize (BN+ReLU) ----------------
template <int C>
__global__ __launch_bounds__(256) void k_norm(const float* __restrict__ Y,
                                              const float* __restrict__ ss,
                                              float* __restrict__ Xo, long n4) {
    const long t = (long)blockIdx.x * 256 + threadIdx.x;
    if (t >= n4) return;
    const float4 y = ((const float4*)Y)[t];
    const int ch = (int)((t * 4) % C);
    float4 o;
    o.x = fmaxf(fmaf(y.x, ss[ch],     ss[C + ch]),     0.f);
    o.y = fmaxf(fmaf(y.y, ss[ch + 1], ss[C + ch + 1]), 0.f);
    o.z = fmaxf(fmaf(y.z, ss[ch + 2], ss[C + ch + 2]), 0.f);
    o.w = fmaxf(fmaf(y.w, ss[ch + 3], ss[C + ch + 3]), 0.f);
    ((float4*)Xo)[t] = o;
}

__global__ __launch_bounds__(256) void k_norm3(float* __restrict__ Y,
                                               const unsigned char* __restrict__ mask,
                                               const float* __restrict__ ss) {
    const long n4 = (long)M_ * COUT / 4;
    const long t = (long)blockIdx.x * 256 + threadIdx.x;
    if (t >= n4) return;
    const long vox = t >> 4;
    const float4 y = ((const float4*)Y)[t];
    const int ch = (int)((t * 4) & 63);
    float4 o;
    if (mask[vox]) {
        o.x = fmaxf(fmaf(y.x, ss[ch],     ss[64 + ch]),     0.f);
        o.y = fmaxf(fmaf(y.y, ss[ch + 1], ss[64 + ch + 1]), 0.f);
        o.z = fmaxf(fmaf(y.z, ss[ch + 2], ss[64 + ch + 2]), 0.f);
        o.w = fmaxf(fmaf(y.w, ss[ch + 3], ss[64 + ch + 3]), 0.f);
    } else {
        o.x = o.y = o.z = o.w = 0.f;
    }
    ((float4*)Y)[t] = o;
}

extern "C" void kernel_launch(void* const* d_in, const int* in_sizes, int n_in,
                              void* d_out, int out_size, void* d_ws, size_t ws_size,
                              hipStream_t stream) {
    const float* feats = (const float*)d_in[0];
    const int*   coords = (const int*)d_in[1];
    const float* W1 = (const float*)d_in[2];
    const float* b1 = (const float*)d_in[3];
    const float* g1 = (const float*)d_in[4];
    const float* be1 = (const float*)d_in[5];
    const float* W2 = (const float*)d_in[6];
    const float* b2 = (const float*)d_in[7];
    const float* g2 = (const float*)d_in[8];
    const float* be2 = (const float*)d_in[9];
    const float* W3 = (const float*)d_in[10];
    const float* b3 = (const float*)d_in[11];
    const float* g3 = (const float*)d_in[12];
    const float* be3 = (const float*)d_in[13];
    float* out = (float*)d_out;

    char* ws = (char*)d_ws;
    const size_t gridBytes = (size_t)B_ * D_ * H_ * W_ * 4;   // 16,777,216
    const size_t bufBytes  = (size_t)N_ * CMID * 4;           // 19,200,000
    int*   grid = (int*)ws;
    float* bufA = (float*)(ws + gridBytes);
    float* bufB = (float*)(ws + gridBytes + bufBytes);
    unsigned char* mask = (unsigned char*)(ws + gridBytes + 2 * bufBytes);
    float* stats = (float*)(ws + gridBytes + 2 * bufBytes + (size_t)M_);

    float* st1 = stats;            // 64
    float* st2 = stats + 64;       // 64
    float* st3 = stats + 128;      // 128
    int*   nact = (int*)(stats + 256);
    float* ss1 = stats + 260;      // 64
    float* ss2 = stats + 324;      // 64
    float* ss3 = stats + 388;      // 128

    hipMemsetAsync(grid, 0xFF, gridBytes, stream);
    hipMemsetAsync(stats, 0, 260 * 4, stream);  // sums + nact

    k_scatter<<<(N_ + 255) / 256, 256, 0, stream>>>(coords, grid);

    const int nb_pts = (N_ + 255) / 256;
    k_subm<CIN, CMID><<<nb_pts, 256, 0, stream>>>(feats, coords, grid, W1, b1, bufA);
    k_stats<CMID><<<512, 256, 0, stream>>>(bufA, (long)N_ * CMID, st1);
    k_finstats<CMID><<<1, 64, 0, stream>>>(st1, g1, be1, (float)N_, nullptr, ss1);
    k_norm<CMID><<<(N_ * CMID / 4 + 255) / 256, 256, 0, stream>>>(bufA, ss1, bufB,
                                                                  (long)N_ * CMID / 4);

    k_subm<CMID, CMID><<<nb_pts, 256, 0, stream>>>(bufB, coords, grid, W2, b2, bufA);
    k_stats<CMID><<<512, 256, 0, stream>>>(bufA, (long)N_ * CMID, st2);
    k_finstats<CMID><<<1, 64, 0, stream>>>(st2, g2, be2, (float)N_, nullptr, ss2);
    k_norm<CMID><<<(N_ * CMID / 4 + 255) / 256, 256, 0, stream>>>(bufA, ss2, bufB,
                                                                  (long)N_ * CMID / 4);

    k_down<<<M_ / 256, 256, 0, stream>>>(bufB, grid, W3, b3, out, mask);
    k_stats3<<<1024, 256, 0, stream>>>(out, mask, st3, nact);
    k_finstats<COUT><<<1, 64, 0, stream>>>(st3, g3, be3, 0.f, nact, ss3);
    k_norm3<<<(M_ * COUT / 4) / 256, 256, 0, stream>>>(out, mask, ss3);
}

// Round 2
// 586.692 us; speedup vs baseline: 1.9169x; 1.9169x over previous
//
#include <hip/hip_runtime.h>

#define B_   2
#define D_   32
#define H_   256
#define W_   256
#define N_   150000
#define CIN  16
#define CMID 32
#define COUT 64
#define DO_  16
#define HO_  128
#define WO_  128
#define M_   (B_*DO_*HO_*WO_)   /* 524288 */
#define EPSf 1e-5f

// ---------------- grid scatter ----------------
__global__ __launch_bounds__(256) void k_scatter(const int* __restrict__ coords,
                                                 int* __restrict__ grid) {
    int i = blockIdx.x * 256 + threadIdx.x;
    if (i >= N_) return;
    const int4 c = *(const int4*)(coords + 4 * (size_t)i);
    grid[((c.x * D_ + c.y) * H_ + c.z) * W_ + c.w] = i;
}

// ---------------- submanifold conv: one wave per point ----------------
// lane = hi*32 + co ; hi selects ci-half. Divergence-free: loop only over
// ballot of active taps (wave-uniform).
template <int CI>
__global__ __launch_bounds__(256) void k_subm(const float* __restrict__ X,
                                              const int* __restrict__ coords,
                                              const int* __restrict__ grid,
                                              const float* __restrict__ Wk,
                                              const float* __restrict__ bias,
                                              float* __restrict__ Y) {
    const int wid  = (blockIdx.x * 256 + threadIdx.x) >> 6;
    const int lane = threadIdx.x & 63;
    if (wid >= N_) return;

    const int4 c4 = *(const int4*)(coords + 4 * (size_t)wid);

    int nidx = -1;
    if (lane < 27) {
        const int nz = c4.y + lane / 9 - 1;
        const int ny = c4.z + (lane / 3) % 3 - 1;
        const int nx = c4.w + lane % 3 - 1;
        if ((unsigned)nz < (unsigned)D_ && (unsigned)ny < (unsigned)H_ &&
            (unsigned)nx < (unsigned)W_)
            nidx = grid[((c4.x * D_ + nz) * H_ + ny) * W_ + nx];
    }
    unsigned long long act = __ballot(nidx >= 0);

    const int hi = lane >> 5;      // ci half
    const int co = lane & 31;
    float acc = 0.f;

    while (act) {
        const int ki = __builtin_ctzll(act);
        act &= act - 1;
        const int ni = __shfl(nidx, ki, 64);
        const float* __restrict__ f = X + (size_t)ni * CI + hi * (CI / 2);
        const float* __restrict__ w = Wk + ((size_t)ki * CI + hi * (CI / 2)) * 32 + co;
#pragma unroll
        for (int c4i = 0; c4i < CI / 8; ++c4i) {
            const float4 fv = *(const float4*)(f + c4i * 4);
            acc = fmaf(fv.x, w[(c4i * 4 + 0) * 32], acc);
            acc = fmaf(fv.y, w[(c4i * 4 + 1) * 32], acc);
            acc = fmaf(fv.z, w[(c4i * 4 + 2) * 32], acc);
            acc = fmaf(fv.w, w[(c4i * 4 + 3) * 32], acc);
        }
    }

    acc += __shfl_xor(acc, 32, 64);       // combine ci halves
    if (lane < 32) Y[(size_t)wid * 32 + lane] = acc + bias[lane];
}

// ---------------- strided down conv: one wave per output voxel ----------------
// lane = co (64 out channels). Probe 27 taps with one gather (lane=ki).
__global__ __launch_bounds__(256) void k_down(const float* __restrict__ X,
                                              const int* __restrict__ grid,
                                              const float* __restrict__ Wk,
                                              const float* __restrict__ bias,
                                              float* __restrict__ Y,
                                              unsigned char* __restrict__ mask) {
    const int wid  = (blockIdx.x * 256 + threadIdx.x) >> 6;
    const int lane = threadIdx.x & 63;
    if (wid >= M_) return;

    const int ox = wid % WO_;
    int t = wid / WO_;
    const int oy = t % HO_;
    t /= HO_;
    const int oz = t % DO_;
    const int b  = t / DO_;

    int nidx = -1;
    if (lane < 27) {
        const int z = 2 * oz - 1 + lane / 9;
        const int y = 2 * oy - 1 + (lane / 3) % 3;
        const int x = 2 * ox - 1 + lane % 3;
        if ((unsigned)z < (unsigned)D_ && (unsigned)y < (unsigned)H_ &&
            (unsigned)x < (unsigned)W_)
            nidx = grid[((b * D_ + z) * H_ + y) * W_ + x];
    }
    unsigned long long act = __ballot(nidx >= 0);
    const int cnt = __popcll(act);

    float acc = 0.f;
    while (act) {
        const int ki = __builtin_ctzll(act);
        act &= act - 1;
        const int ni = __shfl(nidx, ki, 64);
        const float* __restrict__ f = X + (size_t)ni * CMID;
        const float* __restrict__ w = Wk + (size_t)ki * CMID * COUT + lane;
#pragma unroll
        for (int c4i = 0; c4i < CMID / 4; ++c4i) {
            const float4 fv = *(const float4*)(f + c4i * 4);
            acc = fmaf(fv.x, w[(c4i * 4 + 0) * COUT], acc);
            acc = fmaf(fv.y, w[(c4i * 4 + 1) * COUT], acc);
            acc = fmaf(fv.z, w[(c4i * 4 + 2) * COUT], acc);
            acc = fmaf(fv.w, w[(c4i * 4 + 3) * COUT], acc);
        }
    }

    if (lane == 0) mask[wid] = (cnt > 0) ? 1 : 0;
    const float ov = (cnt > 0) ? acc + bias[lane] : 0.f;
    Y[(size_t)wid * COUT + lane] = ov;
}

// ---------------- per-channel sum / sumsq ----------------
template <int C>
__global__ __launch_bounds__(256) void k_stats(const float* __restrict__ Y,
                                               long n_elems,
                                               float* __restrict__ stats) {
    __shared__ float sdata[256];
    const int t = threadIdx.x;
    const long stride = (long)gridDim.x * 256;
    float s = 0.f, s2 = 0.f;
    for (long idx = (long)blockIdx.x * 256 + t; idx < n_elems; idx += stride) {
        const float v = Y[idx];
        s += v; s2 += v * v;
    }
    sdata[t] = s; __syncthreads();
    for (int off = 128; off >= C; off >>= 1) {
        if (t < off) sdata[t] += sdata[t + off];
        __syncthreads();
    }
    if (t < C) atomicAdd(stats + t, sdata[t]);
    __syncthreads();
    sdata[t] = s2; __syncthreads();
    for (int off = 128; off >= C; off >>= 1) {
        if (t < off) sdata[t] += sdata[t + off];
        __syncthreads();
    }
    if (t < C) atomicAdd(stats + C + t, sdata[t]);
}

// stage-3 stats: inactive voxels hold 0 so sums need no mask; nact does.
__global__ __launch_bounds__(256) void k_stats3(const float* __restrict__ Y,
                                                const unsigned char* __restrict__ mask,
                                                float* __restrict__ stats,
                                                int* __restrict__ nact) {
    __shared__ float sdata[256];
    __shared__ int   scnt[256];
    const int t = threadIdx.x;
    const long total  = (long)M_ * COUT;
    const long stride = (long)gridDim.x * 256;
    float s = 0.f, s2 = 0.f;
    int cnt = 0;
    for (long idx = (long)blockIdx.x * 256 + t; idx < total; idx += stride) {
        const float v = Y[idx];
        s += v; s2 += v * v;
        if ((idx & 63) == 0) cnt += mask[idx >> 6];
    }
    sdata[t] = s; __syncthreads();
    for (int off = 128; off >= 64; off >>= 1) {
        if (t < off) sdata[t] += sdata[t + off];
        __syncthreads();
    }
    if (t < 64) atomicAdd(stats + t, sdata[t]);
    __syncthreads();
    sdata[t] = s2; __syncthreads();
    for (int off = 128; off >= 64; off >>= 1) {
        if (t < off) sdata[t] += sdata[t + off];
        __syncthreads();
    }
    if (t < 64) atomicAdd(stats + 64 + t, sdata[t]);
    __syncthreads();
    scnt[t] = cnt; __syncthreads();
    for (int off = 128; off >= 1; off >>= 1) {
        if (t < off) scnt[t] += scnt[t + off];
        __syncthreads();
    }
    if (t == 0) atomicAdd(nact, scnt[0]);
}

// ---------------- finalize scale/shift ----------------
template <int C>
__global__ void k_finstats(const float* __restrict__ stats,
                           const float* __restrict__ g,
                           const float* __restrict__ be,
                           float nfix, const int* __restrict__ nact,
                           float* __restrict__ ss) {
    const int c = threadIdx.x;
    if (c >= C) return;
    float n = nfix;
    if (nact) { int na = *nact; n = (float)(na > 0 ? na : 1); }
    const float m  = stats[c] / n;
    const float v  = stats[C + c] / n - m * m;
    const float sc = g[c] * rsqrtf(v + EPSf);
    ss[c]     = sc;
    ss[C + c] = be[c] - m * sc;
}

// ---------------- normalize (BN+ReLU) ----------------
template <int C>
__global__ __launch_bounds__(256) void k_norm(const float* __restrict__ Y,
                                              const float* __restrict__ ss,
                                              float* __restrict__ Xo, long n4) {
    const long t = (long)blockIdx.x * 256 + threadIdx.x;
    if (t >= n4) return;
    const float4 y = ((const float4*)Y)[t];
    const int ch = (int)((t * 4) % C);
    float4 o;
    o.x = fmaxf(fmaf(y.x, ss[ch],     ss[C + ch]),     0.f);
    o.y = fmaxf(fmaf(y.y, ss[ch + 1], ss[C + ch + 1]), 0.f);
    o.z = fmaxf(fmaf(y.z, ss[ch + 2], ss[C + ch + 2]), 0.f);
    o.w = fmaxf(fmaf(y.w, ss[ch + 3], ss[C + ch + 3]), 0.f);
    ((float4*)Xo)[t] = o;
}

__global__ __launch_bounds__(256) void k_norm3(float* __restrict__ Y,
                                               const unsigned char* __restrict__ mask,
                                               const float* __restrict__ ss) {
    const long n4 = (long)M_ * COUT / 4;
    const long t = (long)blockIdx.x * 256 + threadIdx.x;
    if (t >= n4) return;
    const long vox = t >> 4;
    const float4 y = ((const float4*)Y)[t];
    const int ch = (int)((t * 4) & 63);
    float4 o;
    if (mask[vox]) {
        o.x = fmaxf(fmaf(y.x, ss[ch],     ss[64 + ch]),     0.f);
        o.y = fmaxf(fmaf(y.y, ss[ch + 1], ss[64 + ch + 1]), 0.f);
        o.z = fmaxf(fmaf(y.z, ss[ch + 2], ss[64 + ch + 2]), 0.f);
        o.w = fmaxf(fmaf(y.w, ss[ch + 3], ss[64 + ch + 3]), 0.f);
    } else {
        o.x = o.y = o.z = o.w = 0.f;
    }
    ((float4*)Y)[t] = o;
}

extern "C" void kernel_launch(void* const* d_in, const int* in_sizes, int n_in,
                              void* d_out, int out_size, void* d_ws, size_t ws_size,
                              hipStream_t stream) {
    const float* feats = (const float*)d_in[0];
    const int*   coords = (const int*)d_in[1];
    const float* W1 = (const float*)d_in[2];
    const float* b1 = (const float*)d_in[3];
    const float* g1 = (const float*)d_in[4];
    const float* be1 = (const float*)d_in[5];
    const float* W2 = (const float*)d_in[6];
    const float* b2 = (const float*)d_in[7];
    const float* g2 = (const float*)d_in[8];
    const float* be2 = (const float*)d_in[9];
    const float* W3 = (const float*)d_in[10];
    const float* b3 = (const float*)d_in[11];
    const float* g3 = (const float*)d_in[12];
    const float* be3 = (const float*)d_in[13];
    float* out = (float*)d_out;

    char* ws = (char*)d_ws;
    const size_t gridBytes = (size_t)B_ * D_ * H_ * W_ * 4;   // 16,777,216
    const size_t bufBytes  = (size_t)N_ * CMID * 4;           // 19,200,000
    int*   grid = (int*)ws;
    float* bufA = (float*)(ws + gridBytes);
    float* bufB = (float*)(ws + gridBytes + bufBytes);
    unsigned char* mask = (unsigned char*)(ws + gridBytes + 2 * bufBytes);
    float* stats = (float*)(ws + gridBytes + 2 * bufBytes + (size_t)M_);

    float* st1 = stats;            // 64
    float* st2 = stats + 64;       // 64
    float* st3 = stats + 128;      // 128
    int*   nact = (int*)(stats + 256);
    float* ss1 = stats + 260;      // 64
    float* ss2 = stats + 324;      // 64
    float* ss3 = stats + 388;      // 128

    hipMemsetAsync(grid, 0xFF, gridBytes, stream);
    hipMemsetAsync(stats, 0, 260 * 4, stream);  // sums + nact

    k_scatter<<<(N_ + 255) / 256, 256, 0, stream>>>(coords, grid);

    // one wave (64 threads) per point: 4 waves per 256-block
    const int nb_subm = (N_ + 3) / 4;
    k_subm<CIN><<<nb_subm, 256, 0, stream>>>(feats, coords, grid, W1, b1, bufA);
    k_stats<CMID><<<512, 256, 0, stream>>>(bufA, (long)N_ * CMID, st1);
    k_finstats<CMID><<<1, 64, 0, stream>>>(st1, g1, be1, (float)N_, nullptr, ss1);
    k_norm<CMID><<<(N_ * CMID / 4 + 255) / 256, 256, 0, stream>>>(bufA, ss1, bufB,
                                                                  (long)N_ * CMID / 4);

    k_subm<CMID><<<nb_subm, 256, 0, stream>>>(bufB, coords, grid, W2, b2, bufA);
    k_stats<CMID><<<512, 256, 0, stream>>>(bufA, (long)N_ * CMID, st2);
    k_finstats<CMID><<<1, 64, 0, stream>>>(st2, g2, be2, (float)N_, nullptr, ss2);
    k_norm<CMID><<<(N_ * CMID / 4 + 255) / 256, 256, 0, stream>>>(bufA, ss2, bufB,
                                                                  (long)N_ * CMID / 4);

    // one wave per output voxel: M_/4 blocks of 256
    k_down<<<M_ / 4, 256, 0, stream>>>(bufB, grid, W3, b3, out, mask);
    k_stats3<<<1024, 256, 0, stream>>>(out, mask, st3, nact);
    k_finstats<COUT><<<1, 64, 0, stream>>>(st3, g3, be3, 0.f, nact, ss3);
    k_norm3<<<(M_ * COUT / 4) / 256, 256, 0, stream>>>(out, mask, ss3);
}

// Round 3
// 496.918 us; speedup vs baseline: 2.2632x; 1.1807x over previous
//
#include <hip/hip_runtime.h>

#define B_   2
#define D_   32
#define H_   256
#define W_   256
#define N_   150000
#define CIN  16
#define CMID 32
#define COUT 64
#define DO_  16
#define HO_  128
#define WO_  128
#define M_   (B_*DO_*HO_*WO_)   /* 524288 */
#define EPSf 1e-5f
#define NB_DOWN 8192             /* k_down blocks; %8==0, 32 vox-pairs per block */

// ---------------- grid scatter ----------------
__global__ __launch_bounds__(256) void k_scatter(const int* __restrict__ coords,
                                                 int* __restrict__ grid) {
    int i = blockIdx.x * 256 + threadIdx.x;
    if (i >= N_) return;
    const int4 c = *(const int4*)(coords + 4 * (size_t)i);
    grid[((c.x * D_ + c.y) * H_ + c.z) * W_ + c.w] = i;
}

// ---------------- submanifold conv: one wave per POINT-PAIR ----------------
// Probe: lanes 0-26 -> point A taps, lanes 32-58 -> point B taps (one gather).
// Compute: lane = hi*32+co, hi = ci-half. Two independent tap chains (ILP).
template <int CI>
__global__ __launch_bounds__(256) void k_subm(const float* __restrict__ X,
                                              const int* __restrict__ coords,
                                              const int* __restrict__ grid,
                                              const float* __restrict__ Wk,
                                              const float* __restrict__ bias,
                                              float* __restrict__ Y) {
    const int pid  = (blockIdx.x * 256 + threadIdx.x) >> 6;   // pair id (exact launch)
    const int lane = threadIdx.x & 63;
    const int sub  = lane & 31;
    const int half = lane >> 5;
    const int iA   = pid * 2;

    const int4 cA = *(const int4*)(coords + 4 * (size_t)iA);
    const int4 cB = *(const int4*)(coords + 4 * (size_t)(iA + 1));
    const int4 cc = half ? cB : cA;

    int nidx = -1;
    if (sub < 27) {
        const int nz = cc.y + sub / 9 - 1;
        const int ny = cc.z + (sub / 3) % 3 - 1;
        const int nx = cc.w + sub % 3 - 1;
        if ((unsigned)nz < (unsigned)D_ && (unsigned)ny < (unsigned)H_ &&
            (unsigned)nx < (unsigned)W_)
            nidx = grid[((cc.x * D_ + nz) * H_ + ny) * W_ + nx];
    }
    const unsigned long long act = __ballot(nidx >= 0);
    unsigned int actA = (unsigned int)(act & 0x7FFFFFFull);
    unsigned int actB = (unsigned int)((act >> 32) & 0x7FFFFFFull);

    const int hi = half;          // ci-half for compute
    const int co = sub;
    float accA = 0.f, accB = 0.f;

    while (actA | actB) {
        if (actA) {
            const int ki = __builtin_ctz(actA); actA &= actA - 1;
            const int ni = __shfl(nidx, ki, 64);
            const float* __restrict__ f = X + (size_t)ni * CI + hi * (CI / 2);
            const float* __restrict__ w = Wk + ((size_t)ki * CI + hi * (CI / 2)) * 32 + co;
#pragma unroll
            for (int q = 0; q < CI / 8; ++q) {
                const float4 fv = *(const float4*)(f + q * 4);
                accA = fmaf(fv.x, w[(q * 4 + 0) * 32], accA);
                accA = fmaf(fv.y, w[(q * 4 + 1) * 32], accA);
                accA = fmaf(fv.z, w[(q * 4 + 2) * 32], accA);
                accA = fmaf(fv.w, w[(q * 4 + 3) * 32], accA);
            }
        }
        if (actB) {
            const int ki = __builtin_ctz(actB); actB &= actB - 1;
            const int ni = __shfl(nidx, ki + 32, 64);
            const float* __restrict__ f = X + (size_t)ni * CI + hi * (CI / 2);
            const float* __restrict__ w = Wk + ((size_t)ki * CI + hi * (CI / 2)) * 32 + co;
#pragma unroll
            for (int q = 0; q < CI / 8; ++q) {
                const float4 fv = *(const float4*)(f + q * 4);
                accB = fmaf(fv.x, w[(q * 4 + 0) * 32], accB);
                accB = fmaf(fv.y, w[(q * 4 + 1) * 32], accB);
                accB = fmaf(fv.z, w[(q * 4 + 2) * 32], accB);
                accB = fmaf(fv.w, w[(q * 4 + 3) * 32], accB);
            }
        }
    }

    accA += __shfl_xor(accA, 32, 64);     // combine ci halves
    accB += __shfl_xor(accB, 32, 64);
    const float outv = (half ? accB : accA) + bias[sub];
    Y[(size_t)(iA + half) * 32 + sub] = outv;
}

// ---------------- strided down conv: one wave per OUTPUT-VOXEL-PAIR ----------
// XCD-chunk swizzle: each XCD gets a contiguous 1/8 of output space so the
// grid slice (~2MB) + X slice (~2.4MB) are L2-resident. Stage-3 BN stats are
// fused (register accum -> block reduce -> bounded atomics).
__global__ __launch_bounds__(256) void k_down(const float* __restrict__ X,
                                              const int* __restrict__ grid,
                                              const float* __restrict__ Wk,
                                              const float* __restrict__ bias,
                                              float* __restrict__ Y,
                                              unsigned char* __restrict__ mask,
                                              float* __restrict__ stats,
                                              int* __restrict__ nact) {
    const int b    = blockIdx.x;
    const int swz  = (b & 7) * (NB_DOWN / 8) + (b >> 3);
    const int wv   = threadIdx.x >> 6;
    const int lane = threadIdx.x & 63;
    const int sub  = lane & 31;
    const int half = lane >> 5;

    // block covers 64 consecutive voxels: one half-row (oy,oz,bb constant)
    const int vox0 = swz * 64;
    const int ox0  = vox0 & 127;
    int t = vox0 >> 7;
    const int oy = t & 127; t >>= 7;
    const int oz = t & 15;
    const int bb = t >> 4;

    const int dz = sub / 9, dy = (sub / 3) % 3, dx = sub % 3;
    const int z = 2 * oz - 1 + dz;
    const int y = 2 * oy - 1 + dy;
    const bool zyok = ((unsigned)z < (unsigned)D_) && ((unsigned)y < (unsigned)H_) && (sub < 27);
    const int rowbase = ((bb * D_ + (zyok ? z : 0)) * H_ + (zyok ? y : 0)) * W_;

    const float bv = bias[lane];
    float s = 0.f, s2 = 0.f;
    int cnt = 0;

    for (int it = 0; it < 8; ++it) {
        const int pr  = wv * 8 + it;          // pair index within block (0..31)
        const int ox  = ox0 + pr * 2 + half;  // lanes<32: voxel A, lanes>=32: voxel B
        const int x   = 2 * ox - 1 + dx;

        int nidx = -1;
        if (zyok && (unsigned)x < (unsigned)W_)
            nidx = grid[rowbase + x];

        const unsigned long long act = __ballot(nidx >= 0);
        unsigned int actA = (unsigned int)(act & 0x7FFFFFFull);
        unsigned int actB = (unsigned int)((act >> 32) & 0x7FFFFFFull);
        const int mkA = actA ? 1 : 0;
        const int mkB = actB ? 1 : 0;

        float accA = 0.f, accB = 0.f;
        while (actA | actB) {
            if (actA) {
                const int ki = __builtin_ctz(actA); actA &= actA - 1;
                const int ni = __shfl(nidx, ki, 64);
                const float* __restrict__ f = X + (size_t)ni * CMID;
                const float* __restrict__ w = Wk + (size_t)ki * CMID * COUT + lane;
#pragma unroll
                for (int q = 0; q < CMID / 4; ++q) {
                    const float4 fv = *(const float4*)(f + q * 4);
                    accA = fmaf(fv.x, w[(q * 4 + 0) * COUT], accA);
                    accA = fmaf(fv.y, w[(q * 4 + 1) * COUT], accA);
                    accA = fmaf(fv.z, w[(q * 4 + 2) * COUT], accA);
                    accA = fmaf(fv.w, w[(q * 4 + 3) * COUT], accA);
                }
            }
            if (actB) {
                const int ki = __builtin_ctz(actB); actB &= actB - 1;
                const int ni = __shfl(nidx, ki + 32, 64);
                const float* __restrict__ f = X + (size_t)ni * CMID;
                const float* __restrict__ w = Wk + (size_t)ki * CMID * COUT + lane;
#pragma unroll
                for (int q = 0; q < CMID / 4; ++q) {
                    const float4 fv = *(const float4*)(f + q * 4);
                    accB = fmaf(fv.x, w[(q * 4 + 0) * COUT], accB);
                    accB = fmaf(fv.y, w[(q * 4 + 1) * COUT], accB);
                    accB = fmaf(fv.z, w[(q * 4 + 2) * COUT], accB);
                    accB = fmaf(fv.w, w[(q * 4 + 3) * COUT], accB);
                }
            }
        }

        const int vA = vox0 + pr * 2;
        const float oA = mkA ? accA + bv : 0.f;
        const float oB = mkB ? accB + bv : 0.f;
        Y[(size_t)vA * COUT + lane]       = oA;
        Y[(size_t)(vA + 1) * COUT + lane] = oB;
        if (lane == 0) {
            mask[vA]     = (unsigned char)mkA;
            mask[vA + 1] = (unsigned char)mkB;
            cnt += mkA + mkB;
        }
        s  += oA + oB;
        s2 += oA * oA + oB * oB;
    }

    // block reduction of per-channel sums (channel = lane, 4 waves)
    __shared__ float sd[256];
    __shared__ int   scnt[4];
    const int tid = threadIdx.x;
    sd[tid] = s;
    if (lane == 0) scnt[wv] = cnt;
    __syncthreads();
    if (tid < 64) atomicAdd(stats + tid, sd[tid] + sd[tid + 64] + sd[tid + 128] + sd[tid + 192]);
    __syncthreads();
    sd[tid] = s2;
    __syncthreads();
    if (tid < 64) atomicAdd(stats + 64 + tid, sd[tid] + sd[tid + 64] + sd[tid + 128] + sd[tid + 192]);
    if (tid == 0) atomicAdd(nact, scnt[0] + scnt[1] + scnt[2] + scnt[3]);
}

// ---------------- per-channel sum / sumsq (stages 1,2) ----------------
template <int C>
__global__ __launch_bounds__(256) void k_stats(const float* __restrict__ Y,
                                               long n_elems,
                                               float* __restrict__ stats) {
    __shared__ float sdata[256];
    const int t = threadIdx.x;
    const long stride = (long)gridDim.x * 256;
    float s = 0.f, s2 = 0.f;
    for (long idx = (long)blockIdx.x * 256 + t; idx < n_elems; idx += stride) {
        const float v = Y[idx];
        s += v; s2 += v * v;
    }
    sdata[t] = s; __syncthreads();
    for (int off = 128; off >= C; off >>= 1) {
        if (t < off) sdata[t] += sdata[t + off];
        __syncthreads();
    }
    if (t < C) atomicAdd(stats + t, sdata[t]);
    __syncthreads();
    sdata[t] = s2; __syncthreads();
    for (int off = 128; off >= C; off >>= 1) {
        if (t < off) sdata[t] += sdata[t + off];
        __syncthreads();
    }
    if (t < C) atomicAdd(stats + C + t, sdata[t]);
}

// ---------------- finalize scale/shift ----------------
template <int C>
__global__ void k_finstats(const float* __restrict__ stats,
                           const float* __restrict__ g,
                           const float* __restrict__ be,
                           float nfix, const int* __restrict__ nact,
                           float* __restrict__ ss) {
    const int c = threadIdx.x;
    if (c >= C) return;
    float n = nfix;
    if (nact) { int na = *nact; n = (float)(na > 0 ? na : 1); }
    const float m  = stats[c] / n;
    const float v  = stats[C + c] / n - m * m;
    const float sc = g[c] * rsqrtf(v + EPSf);
    ss[c]     = sc;
    ss[C + c] = be[c] - m * sc;
}

// ---------------- normalize (BN+ReLU) ----------------
template <int C>
__global__ __launch_bounds__(256) void k_norm(const float* __restrict__ Y,
                                              const float* __restrict__ ss,
                                              float* __restrict__ Xo, long n4) {
    const long t = (long)blockIdx.x * 256 + threadIdx.x;
    if (t >= n4) return;
    const float4 y = ((const float4*)Y)[t];
    const int ch = (int)((t * 4) % C);
    float4 o;
    o.x = fmaxf(fmaf(y.x, ss[ch],     ss[C + ch]),     0.f);
    o.y = fmaxf(fmaf(y.y, ss[ch + 1], ss[C + ch + 1]), 0.f);
    o.z = fmaxf(fmaf(y.z, ss[ch + 2], ss[C + ch + 2]), 0.f);
    o.w = fmaxf(fmaf(y.w, ss[ch + 3], ss[C + ch + 3]), 0.f);
    ((float4*)Xo)[t] = o;
}

__global__ __launch_bounds__(256) void k_norm3(float* __restrict__ Y,
                                               const unsigned char* __restrict__ mask,
                                               const float* __restrict__ ss) {
    const long n4 = (long)M_ * COUT / 4;
    const long t = (long)blockIdx.x * 256 + threadIdx.x;
    if (t >= n4) return;
    const long vox = t >> 4;
    const float4 y = ((const float4*)Y)[t];
    const int ch = (int)((t * 4) & 63);
    float4 o;
    if (mask[vox]) {
        o.x = fmaxf(fmaf(y.x, ss[ch],     ss[64 + ch]),     0.f);
        o.y = fmaxf(fmaf(y.y, ss[ch + 1], ss[64 + ch + 1]), 0.f);
        o.z = fmaxf(fmaf(y.z, ss[ch + 2], ss[64 + ch + 2]), 0.f);
        o.w = fmaxf(fmaf(y.w, ss[ch + 3], ss[64 + ch + 3]), 0.f);
    } else {
        o.x = o.y = o.z = o.w = 0.f;
    }
    ((float4*)Y)[t] = o;
}

extern "C" void kernel_launch(void* const* d_in, const int* in_sizes, int n_in,
                              void* d_out, int out_size, void* d_ws, size_t ws_size,
                              hipStream_t stream) {
    const float* feats = (const float*)d_in[0];
    const int*   coords = (const int*)d_in[1];
    const float* W1 = (const float*)d_in[2];
    const float* b1 = (const float*)d_in[3];
    const float* g1 = (const float*)d_in[4];
    const float* be1 = (const float*)d_in[5];
    const float* W2 = (const float*)d_in[6];
    const float* b2 = (const float*)d_in[7];
    const float* g2 = (const float*)d_in[8];
    const float* be2 = (const float*)d_in[9];
    const float* W3 = (const float*)d_in[10];
    const float* b3 = (const float*)d_in[11];
    const float* g3 = (const float*)d_in[12];
    const float* be3 = (const float*)d_in[13];
    float* out = (float*)d_out;

    char* ws = (char*)d_ws;
    const size_t gridBytes = (size_t)B_ * D_ * H_ * W_ * 4;   // 16,777,216
    const size_t bufBytes  = (size_t)N_ * CMID * 4;           // 19,200,000
    int*   grid = (int*)ws;
    float* bufA = (float*)(ws + gridBytes);
    float* bufB = (float*)(ws + gridBytes + bufBytes);
    unsigned char* mask = (unsigned char*)(ws + gridBytes + 2 * bufBytes);
    float* stats = (float*)(ws + gridBytes + 2 * bufBytes + (size_t)M_);

    float* st1 = stats;            // 64
    float* st2 = stats + 64;       // 64
    float* st3 = stats + 128;      // 128
    int*   nact = (int*)(stats + 256);
    float* ss1 = stats + 260;      // 64
    float* ss2 = stats + 324;      // 64
    float* ss3 = stats + 388;      // 128

    hipMemsetAsync(grid, 0xFF, gridBytes, stream);
    hipMemsetAsync(stats, 0, 260 * 4, stream);  // sums + nact

    k_scatter<<<(N_ + 255) / 256, 256, 0, stream>>>(coords, grid);

    // one wave per point-PAIR: 75000 pairs, 4 waves/block
    const int nb_subm = 75000 / 4;   // 18750, exact
    k_subm<CIN><<<nb_subm, 256, 0, stream>>>(feats, coords, grid, W1, b1, bufA);
    k_stats<CMID><<<512, 256, 0, stream>>>(bufA, (long)N_ * CMID, st1);
    k_finstats<CMID><<<1, 64, 0, stream>>>(st1, g1, be1, (float)N_, nullptr, ss1);
    k_norm<CMID><<<(N_ * CMID / 4 + 255) / 256, 256, 0, stream>>>(bufA, ss1, bufB,
                                                                  (long)N_ * CMID / 4);

    k_subm<CMID><<<nb_subm, 256, 0, stream>>>(bufB, coords, grid, W2, b2, bufA);
    k_stats<CMID><<<512, 256, 0, stream>>>(bufA, (long)N_ * CMID, st2);
    k_finstats<CMID><<<1, 64, 0, stream>>>(st2, g2, be2, (float)N_, nullptr, ss2);
    k_norm<CMID><<<(N_ * CMID / 4 + 255) / 256, 256, 0, stream>>>(bufA, ss2, bufB,
                                                                  (long)N_ * CMID / 4);

    // down conv + fused stage-3 stats
    k_down<<<NB_DOWN, 256, 0, stream>>>(bufB, grid, W3, b3, out, mask, st3, nact);
    k_finstats<COUT><<<1, 64, 0, stream>>>(st3, g3, be3, 0.f, nact, ss3);
    k_norm3<<<(M_ * COUT / 4) / 256, 256, 0, stream>>>(out, mask, ss3);
}